// Round 5
// baseline (311.774 us; speedup 1.0000x reference)
//
#include <hip/hip_runtime.h>
#include <stdint.h>

// Problem constants: B=4, S=2048, D=1024, H=1024, heads=16, d_k=64.
// Pipeline: fused cast->bf16, fused QKV GEMM (MFMA, LDS-bounced coalesced
// epilogues, V transposed per head), flash attention (MFMA, no-max exp2
// softmax via raw v_exp_f32, S^T trick, perm-packed bf16, SINGLE-BARRIER
// double-buffered K/V prefetch), out GEMM (single-barrier prefetch, f32 out).
// LDS tiles XOR-swizzled (granule g of row r at g^(r&7)) -> conflict-free b128.

using bf16x8 = __attribute__((ext_vector_type(8))) short;   // 8 bf16 = 4 VGPRs
using f32x4  = __attribute__((ext_vector_type(4))) float;   // MFMA C/D frag

#define QSCALE 0.18033688f  // 1/sqrt(64) * log2(e): scores come out log2-scaled -> exp2

__device__ __forceinline__ unsigned short f2bf(float f) {
    unsigned u = __builtin_bit_cast(unsigned, f);
    u += 0x7fffu + ((u >> 16) & 1u);          // RNE
    return (unsigned short)(u >> 16);
}

// pack two f32 -> two bf16 in one dword: round-to-nearest (ties away) + v_perm
__device__ __forceinline__ unsigned pack2bf(float f0, float f1) {
    unsigned u0 = __builtin_bit_cast(unsigned, f0) + 0x8000u;
    unsigned u1 = __builtin_bit_cast(unsigned, f1) + 0x8000u;
    return __builtin_amdgcn_perm(u1, u0, 0x07060302);  // {hi16(u1),hi16(u0)}
}

// async global->LDS, 16B per lane; LDS dest = wave-uniform base + lane*16
__device__ __forceinline__ void gld16(const void* g, void* l) {
    void* gnc = (void*)g;
    __builtin_amdgcn_global_load_lds((__attribute__((address_space(1))) void*)gnc,
                                     (__attribute__((address_space(3))) void*)l,
                                     16, 0, 0);
}

// swizzled LDS short-offset for (row R, 16B-granule g) in a 64-short-row tile
__device__ __forceinline__ int swz(int R, int g) {
    return R * 64 + ((g ^ (R & 7)) << 3);
}

// ---------------------------------------------------------------- fused casts
__global__ void castall(const float* __restrict__ X, const float* __restrict__ Wq,
                        const float* __restrict__ Wk, const float* __restrict__ Wv,
                        const float* __restrict__ Wo, unsigned short* __restrict__ Xb,
                        unsigned short* __restrict__ Wqkvb, unsigned short* __restrict__ Wob) {
    const int bx = blockIdx.x;
    const float* src; unsigned short* dst; int idx;
    if (bx < 8192) { src = X; dst = Xb; idx = bx * 256 + threadIdx.x; }
    else {
        const int r = bx - 8192, w = r >> 10;
        idx = (r & 1023) * 256 + threadIdx.x;
        src = (w == 0) ? Wq : (w == 1) ? Wk : (w == 2) ? Wv : Wo;
        dst = (w == 3) ? Wob : Wqkvb + (size_t)w * 1048576;
    }
    float4 v = ((const float4*)src)[idx];
    ((uint2*)dst)[idx] = make_uint2(pack2bf(v.x, v.y), pack2bf(v.z, v.w));
}

// ---------------------------------------------------------------- fused QKV GEMM
// A: (8192,1024) bf16. Wqkv: 3 stacked (1024,1024) bf16.
// blockIdx.x: [0,8)=Q, [8,16)=K, [16,24)=V. Q scaled by QSCALE; V stored
// transposed per head: Vt[(b*1024 + n)*2048 + s]. Epilogue bounces the
// 128x128 bf16 tile through LDS (stride 136) for coalesced b128 stores.
// m97 2-barrier structure kept: 6 blocks/CU of work -> cross-block overlap
// already hides staging latency; dbuf's 64KB LDS would cut residency (m132).
__global__ __launch_bounds__(256) void gemm_qkv(const unsigned short* __restrict__ A,
                                                const unsigned short* __restrict__ Wqkv,
                                                const float* __restrict__ bq,
                                                const float* __restrict__ bk,
                                                const float* __restrict__ bv,
                                                unsigned short* __restrict__ Qb,
                                                unsigned short* __restrict__ Kb,
                                                unsigned short* __restrict__ Vt) {
    __shared__ alignas(16) unsigned short smem[17408];   // staging (2x8192) / out-tile (128x136)
    unsigned short* sA = smem;
    unsigned short* sB = smem + 8192;
    unsigned short* OT = smem;

    const int tid  = threadIdx.x;
    const int lane = tid & 63;
    const int wave = tid >> 6;
    const int quad = lane >> 4;
    const int l15  = lane & 15;
    const int lr   = lane >> 3;
    const int lcs  = (((lane & 7) ^ lr) << 3);
    const int nb   = blockIdx.x >> 3;              // 0=Q 1=K 2=V
    const int col0 = (blockIdx.x & 7) * 128;
    const int row0 = blockIdx.y * 128;
    const unsigned short* W = Wqkv + ((size_t)nb << 20);
    const float* bias = (nb == 0) ? bq : (nb == 1) ? bk : bv;
    const int wm = wave >> 1, wn = wave & 1;

    f32x4 acc[4][4];
#pragma unroll
    for (int i = 0; i < 4; i++)
#pragma unroll
        for (int j = 0; j < 4; j++) acc[i][j] = f32x4{0.f, 0.f, 0.f, 0.f};

    for (int kt = 0; kt < 16; ++kt) {
        const int k0 = kt * 64;
#pragma unroll
        for (int i = 0; i < 4; i++) {
            const int c = wave * 4 + i;
            const int r = c * 8 + lr;
            gld16(A + (size_t)(row0 + r) * 1024 + k0 + lcs, &sA[c * 512]);
            gld16(W + (size_t)(col0 + r) * 1024 + k0 + lcs, &sB[c * 512]);
        }
        __syncthreads();
#pragma unroll
        for (int kx = 0; kx < 2; ++kx) {
            bf16x8 a[4], b[4];
#pragma unroll
            for (int i = 0; i < 4; i++) {
                a[i] = *(const bf16x8*)&sA[swz(wm * 64 + i * 16 + l15, kx * 4 + quad)];
                b[i] = *(const bf16x8*)&sB[swz(wn * 64 + i * 16 + l15, kx * 4 + quad)];
            }
#pragma unroll
            for (int i = 0; i < 4; i++)
#pragma unroll
                for (int j = 0; j < 4; j++)
                    acc[i][j] = __builtin_amdgcn_mfma_f32_16x16x32_bf16(a[i], b[j], acc[i][j], 0, 0, 0);
        }
        __syncthreads();
    }

    // ---- epilogue phase 1: acc -> LDS out-tile (stride 136 shorts)
    if (nb != 2) {
        const float sc = (nb == 0) ? QSCALE : 1.0f;
#pragma unroll
        for (int i = 0; i < 4; i++) {
#pragma unroll
            for (int j = 0; j < 4; j++) {
                const int ct  = wn * 64 + j * 16 + l15;
                const float bvv = bias[col0 + ct];
                const int rt  = wm * 64 + i * 16 + quad * 4;
#pragma unroll
                for (int r = 0; r < 4; r++)
                    OT[(rt + r) * 136 + ct] = f2bf((acc[i][j][r] + bvv) * sc);
            }
        }
    } else {
#pragma unroll
        for (int i = 0; i < 4; i++) {
#pragma unroll
            for (int j = 0; j < 4; j++) {
                const int ct  = wn * 64 + j * 16 + l15;          // d within tile
                const float bvv = bias[col0 + ct];
                const int rt  = wm * 64 + i * 16 + quad * 4;     // s within tile
                *(uint2*)&OT[ct * 136 + rt] =
                    make_uint2(pack2bf(acc[i][j][0] + bvv, acc[i][j][1] + bvv),
                               pack2bf(acc[i][j][2] + bvv, acc[i][j][3] + bvv));
            }
        }
    }
    __syncthreads();

    // ---- epilogue phase 2: coalesced b128 stores
    const int rr   = wave * 32 + (lane >> 1);
    const int half = lane & 1;
    if (nb != 2) {
        unsigned short* C = (nb == 0) ? Qb : Kb;
        unsigned short* gdst = C + (size_t)(row0 + rr) * 1024 + col0 + half * 64;
#pragma unroll
        for (int k = 0; k < 8; k++)
            *(bf16x8*)(gdst + k * 8) = *(const bf16x8*)&OT[rr * 136 + half * 64 + k * 8];
    } else {
        const int bb = row0 >> 11, s0l = row0 & 2047;
        unsigned short* gdst = Vt + ((size_t)(bb * 1024 + col0 + rr)) * 2048 + s0l + half * 64;
#pragma unroll
        for (int k = 0; k < 8; k++)
            *(bf16x8*)(gdst + k * 8) = *(const bf16x8*)&OT[rr * 136 + half * 64 + k * 8];
    }
}

// ---------------------------------------------------------------- out GEMM (f32 out)
// Single-barrier prefetch loop: only 2 blocks/CU of work exist, so cross-block
// overlap can't hide staging latency -- prefetch tile kt+1 after the barrier
// that publishes kt. LDS 64KB (dbuf) still fits the 2 resident blocks... (1/CU);
// all 512 blocks are one round anyway.
__global__ __launch_bounds__(256) void gemm_out(const unsigned short* __restrict__ A,
                                                const unsigned short* __restrict__ W,
                                                const float* __restrict__ bias,
                                                float* __restrict__ C) {
    __shared__ alignas(16) unsigned short sA[2][8192];
    __shared__ alignas(16) unsigned short sB[2][8192];
    const int tid  = threadIdx.x;
    const int lane = tid & 63;
    const int wave = tid >> 6;
    const int quad = lane >> 4;
    const int l15  = lane & 15;
    const int lr   = lane >> 3;
    const int lcs  = (((lane & 7) ^ lr) << 3);
    const int row0 = blockIdx.y * 128;
    const int col0 = blockIdx.x * 128;
    const int wm = wave >> 1, wn = wave & 1;

    f32x4 acc[4][4];
#pragma unroll
    for (int i = 0; i < 4; i++)
#pragma unroll
        for (int j = 0; j < 4; j++) acc[i][j] = f32x4{0.f, 0.f, 0.f, 0.f};

#define GO_STAGE(kt_, buf_)                                                        \
    {                                                                              \
        const int k0_ = (kt_) * 64;                                                \
        _Pragma("unroll")                                                          \
        for (int i = 0; i < 4; i++) {                                              \
            const int c = wave * 4 + i;                                            \
            const int r = c * 8 + lr;                                              \
            gld16(A + (size_t)(row0 + r) * 1024 + k0_ + lcs, &sA[buf_][c * 512]);  \
            gld16(W + (size_t)(col0 + r) * 1024 + k0_ + lcs, &sB[buf_][c * 512]);  \
        }                                                                          \
    }

    GO_STAGE(0, 0)
    for (int kt = 0; kt < 16; ++kt) {
        const int buf = kt & 1;
        __syncthreads();                       // publishes buf (drains prefetch)
        if (kt < 15) GO_STAGE(kt + 1, buf ^ 1)
#pragma unroll
        for (int kx = 0; kx < 2; ++kx) {
            bf16x8 a[4], b[4];
#pragma unroll
            for (int i = 0; i < 4; i++) {
                a[i] = *(const bf16x8*)&sA[buf][swz(wm * 64 + i * 16 + l15, kx * 4 + quad)];
                b[i] = *(const bf16x8*)&sB[buf][swz(wn * 64 + i * 16 + l15, kx * 4 + quad)];
            }
#pragma unroll
            for (int i = 0; i < 4; i++)
#pragma unroll
                for (int j = 0; j < 4; j++)
                    acc[i][j] = __builtin_amdgcn_mfma_f32_16x16x32_bf16(a[i], b[j], acc[i][j], 0, 0, 0);
        }
    }
#undef GO_STAGE

#pragma unroll
    for (int i = 0; i < 4; i++) {
#pragma unroll
        for (int j = 0; j < 4; j++) {
            const int col   = col0 + wn * 64 + j * 16 + l15;
            const float bvv = bias[col];
            const int rbase = row0 + wm * 64 + i * 16 + quad * 4;
#pragma unroll
            for (int r = 0; r < 4; r++)
                C[(size_t)(rbase + r) * 1024 + col] = acc[i][j][r] + bvv;
        }
    }
}

// ---------------------------------------------------------------- flash attention
// Q, K: (B*S, 1024) bf16; Q pre-scaled by QSCALE (fold softmax scale + log2e).
// Vt: (B*1024, 2048) bf16. Ctx out: (B*S, 1024) bf16.
// Block: 128 q-rows of one (b,h); wave owns 32 q-rows. 32 k-tiles of 64.
// SINGLE-BARRIER loop: dbuf K/V, prefetch kt+1 issued after the barrier that
// publishes kt -> staging latency overlaps the ~650cyc tile compute. Race-free:
// barrier at kt+1 proves all waves finished reading buf[kt&1] before any wave
// stages kt+2 into it. LDS 50.4KB -> 3 blocks/CU.
__global__ __launch_bounds__(256) void attn(const unsigned short* __restrict__ Q,
                                            const unsigned short* __restrict__ K,
                                            const unsigned short* __restrict__ Vt,
                                            unsigned short* __restrict__ Ctx) {
    __shared__ alignas(16) unsigned short Kl[2][64 * 64];  // [buf][krow][d], swizzled
    __shared__ alignas(16) unsigned short Vl[2][64 * 64];  // [buf][d][krow], swizzled
    __shared__ alignas(16) unsigned short Pl[4][32][72];   // per-wave P

    const int tid  = threadIdx.x;
    const int lane = tid & 63;
    const int wave = tid >> 6;
    const int quad = lane >> 4;
    const int l15  = lane & 15;
    const int lr   = lane >> 3;
    const int lcs  = (((lane & 7) ^ lr) << 3);

    const int qt = blockIdx.x, h = blockIdx.y, b = blockIdx.z;
    const int q0 = qt * 128;
    const size_t tokbase = (size_t)b * 2048;

    bf16x8 qa[2][2];
#pragma unroll
    for (int mt = 0; mt < 2; ++mt)
#pragma unroll
        for (int kx = 0; kx < 2; ++kx)
            qa[mt][kx] = *(const bf16x8*)(Q + (tokbase + q0 + wave * 32 + mt * 16 + l15) * 1024 +
                                          h * 64 + kx * 32 + quad * 8);

    f32x4 O[2][4];
#pragma unroll
    for (int mt = 0; mt < 2; ++mt)
#pragma unroll
        for (int nt = 0; nt < 4; ++nt) O[mt][nt] = f32x4{0.f, 0.f, 0.f, 0.f};
    float rs[2] = {0.f, 0.f};

#define AT_STAGE(kt_, buf_)                                                                     \
    {                                                                                           \
        _Pragma("unroll")                                                                       \
        for (int i = 0; i < 2; i++) {                                                           \
            const int c  = wave * 2 + i;                                                        \
            const int rr = c * 8 + lr;                                                          \
            gld16(K + (tokbase + (kt_) * 64 + rr) * 1024 + h * 64 + lcs, &Kl[buf_][c * 512]);   \
            gld16(Vt + ((size_t)(b * 1024 + h * 64 + rr)) * 2048 + (kt_) * 64 + lcs,            \
                  &Vl[buf_][c * 512]);                                                          \
        }                                                                                       \
    }

    AT_STAGE(0, 0)
    for (int kt = 0; kt < 32; ++kt) {
        const int buf = kt & 1;
        __syncthreads();                     // publishes buf (drains prefetch vmcnt)
        if (kt < 31) AT_STAGE(kt + 1, buf ^ 1)

        // S^T = K @ Q^T  (C layout: row=quad*4+r is K-COL, col=lane&15 is Q-ROW)
        f32x4 St[4][2];
#pragma unroll
        for (int nt = 0; nt < 4; ++nt)
#pragma unroll
            for (int mt = 0; mt < 2; ++mt) St[nt][mt] = f32x4{0.f, 0.f, 0.f, 0.f};
#pragma unroll
        for (int kx = 0; kx < 2; ++kx) {
            bf16x8 kb[4];
#pragma unroll
            for (int nt = 0; nt < 4; ++nt)
                kb[nt] = *(const bf16x8*)&Kl[buf][swz(nt * 16 + l15, kx * 4 + quad)];
#pragma unroll
            for (int nt = 0; nt < 4; ++nt)
#pragma unroll
                for (int mt = 0; mt < 2; ++mt)
                    St[nt][mt] = __builtin_amdgcn_mfma_f32_16x16x32_bf16(kb[nt], qa[mt][kx], St[nt][mt], 0, 0, 0);
        }

        // raw v_exp_f32 (scores pre-scaled by log2e) + perm-pack -> b64 write
#pragma unroll
        for (int mt = 0; mt < 2; ++mt) {
            float rsl = 0.f;
#pragma unroll
            for (int nt = 0; nt < 4; ++nt) {
                float p0 = __builtin_amdgcn_exp2f(St[nt][mt][0]);
                float p1 = __builtin_amdgcn_exp2f(St[nt][mt][1]);
                float p2 = __builtin_amdgcn_exp2f(St[nt][mt][2]);
                float p3 = __builtin_amdgcn_exp2f(St[nt][mt][3]);
                rsl += (p0 + p1) + (p2 + p3);
                *(uint2*)&Pl[wave][mt * 16 + l15][nt * 16 + quad * 4] =
                    make_uint2(pack2bf(p0, p1), pack2bf(p2, p3));
            }
            rs[mt] += rsl;
        }

        // O += P @ V  (per-wave Pl; same-wave LDS ordering via lgkmcnt)
#pragma unroll
        for (int kx = 0; kx < 2; ++kx) {
            bf16x8 pa[2], vb[4];
#pragma unroll
            for (int mt = 0; mt < 2; ++mt)
                pa[mt] = *(const bf16x8*)&Pl[wave][mt * 16 + l15][kx * 32 + quad * 8];
#pragma unroll
            for (int nt = 0; nt < 4; ++nt)
                vb[nt] = *(const bf16x8*)&Vl[buf][swz(nt * 16 + l15, kx * 4 + quad)];
#pragma unroll
            for (int mt = 0; mt < 2; ++mt)
#pragma unroll
                for (int nt = 0; nt < 4; ++nt)
                    O[mt][nt] = __builtin_amdgcn_mfma_f32_16x16x32_bf16(pa[mt], vb[nt], O[mt][nt], 0, 0, 0);
        }
    }
#undef AT_STAGE

    // reduce row-sums across quads (epilogue only)
    float linv[2][4];
#pragma unroll
    for (int mt = 0; mt < 2; ++mt) {
        float lv = rs[mt];
        lv += __shfl_xor(lv, 16);
        lv += __shfl_xor(lv, 32);
#pragma unroll
        for (int r = 0; r < 4; ++r)
            linv[mt][r] = 1.0f / __shfl(lv, quad * 4 + r);
    }

    // normalize + store ctx; O C-layout: row=quad*4+r (qrow), col=l15 (out-d)
#pragma unroll
    for (int mt = 0; mt < 2; ++mt) {
#pragma unroll
        for (int r = 0; r < 4; ++r) {
            const int row   = q0 + wave * 32 + mt * 16 + quad * 4 + r;
            const size_t base = (tokbase + row) * 1024 + h * 64;
#pragma unroll
            for (int nt = 0; nt < 4; ++nt)
                Ctx[base + nt * 16 + l15] = f2bf(O[mt][nt][r] * linv[mt][r]);
        }
    }
}

// ---------------------------------------------------------------- launch
extern "C" void kernel_launch(void* const* d_in, const int* in_sizes, int n_in,
                              void* d_out, int out_size, void* d_ws, size_t ws_size,
                              hipStream_t stream) {
    (void)in_sizes; (void)n_in; (void)out_size; (void)ws_size;
    const float* X  = (const float*)d_in[0];
    const float* Wq = (const float*)d_in[1];
    const float* bq = (const float*)d_in[2];
    const float* Wk = (const float*)d_in[3];
    const float* bk = (const float*)d_in[4];
    const float* Wv = (const float*)d_in[5];
    const float* bv = (const float*)d_in[6];
    const float* Wo = (const float*)d_in[7];
    const float* bo = (const float*)d_in[8];

    char* ws = (char*)d_ws;
    unsigned short* Xb    = (unsigned short*)(ws);                        // 16 MB (aliased as Ctx)
    unsigned short* Qb    = (unsigned short*)(ws + (size_t)16 * 1048576); // 16 MB
    unsigned short* Kb    = (unsigned short*)(ws + (size_t)32 * 1048576); // 16 MB
    unsigned short* Vt    = (unsigned short*)(ws + (size_t)48 * 1048576); // 16 MB
    unsigned short* Wqkvb = (unsigned short*)(ws + (size_t)64 * 1048576); // 6 MB
    unsigned short* Wob   = (unsigned short*)(ws + (size_t)70 * 1048576); // 2 MB
    unsigned short* Ctx   = Xb;  // X dead after QKV GEMM (stream-ordered)

    castall<<<dim3(12288), 256, 0, stream>>>(X, Wq, Wk, Wv, Wo, Xb, Wqkvb, Wob);
    gemm_qkv<<<dim3(24, 64), 256, 0, stream>>>(Xb, Wqkvb, bq, bk, bv, Qb, Kb, Vt);
    attn<<<dim3(16, 16, 4), 256, 0, stream>>>(Qb, Kb, Vt, Ctx);
    gemm_out<<<dim3(8, 64), 256, 0, stream>>>(Ctx, Wob, bo, (float*)d_out);
}

// Round 6
// 281.422 us; speedup vs baseline: 1.1079x; 1.1079x over previous
//
#include <hip/hip_runtime.h>
#include <stdint.h>

// Problem constants: B=4, S=2048, D=1024, H=1024, heads=16, d_k=64.
// Pipeline: fused cast->bf16, fused QKV GEMM (MFMA, LDS-bounced coalesced
// epilogues, V transposed per head), flash attention (MFMA, no-max exp2
// softmax, S^T trick, MFMA row-sums, 256-q tile / 8 waves, single-barrier
// dbuf K/V prefetch), out GEMM (m97 2-barrier, f32 out).
// LDS tiles XOR-swizzled (granule g of row r at g^(r&7)) -> conflict-free b128.

using bf16x8 = __attribute__((ext_vector_type(8))) short;   // 8 bf16 = 4 VGPRs
using f32x4  = __attribute__((ext_vector_type(4))) float;   // MFMA C/D frag

#define QSCALE 0.18033688f  // 1/sqrt(64) * log2(e): scores come out log2-scaled -> exp2

__device__ __forceinline__ unsigned short f2bf(float f) {
    unsigned u = __builtin_bit_cast(unsigned, f);
    u += 0x7fffu + ((u >> 16) & 1u);          // RNE
    return (unsigned short)(u >> 16);
}

// pack two f32 -> two bf16 in one dword: round-to-nearest (ties away) + v_perm
__device__ __forceinline__ unsigned pack2bf(float f0, float f1) {
    unsigned u0 = __builtin_bit_cast(unsigned, f0) + 0x8000u;
    unsigned u1 = __builtin_bit_cast(unsigned, f1) + 0x8000u;
    return __builtin_amdgcn_perm(u1, u0, 0x07060302);  // {hi16(u1),hi16(u0)}
}

// async global->LDS, 16B per lane; LDS dest = wave-uniform base + lane*16
__device__ __forceinline__ void gld16(const void* g, void* l) {
    void* gnc = (void*)g;
    __builtin_amdgcn_global_load_lds((__attribute__((address_space(1))) void*)gnc,
                                     (__attribute__((address_space(3))) void*)l,
                                     16, 0, 0);
}

// swizzled LDS short-offset for (row R, 16B-granule g) in a 64-short-row tile
__device__ __forceinline__ int swz(int R, int g) {
    return R * 64 + ((g ^ (R & 7)) << 3);
}

// ---------------------------------------------------------------- fused casts
__global__ void castall(const float* __restrict__ X, const float* __restrict__ Wq,
                        const float* __restrict__ Wk, const float* __restrict__ Wv,
                        const float* __restrict__ Wo, unsigned short* __restrict__ Xb,
                        unsigned short* __restrict__ Wqkvb, unsigned short* __restrict__ Wob) {
    const int bx = blockIdx.x;
    const float* src; unsigned short* dst; int idx;
    if (bx < 8192) { src = X; dst = Xb; idx = bx * 256 + threadIdx.x; }
    else {
        const int r = bx - 8192, w = r >> 10;
        idx = (r & 1023) * 256 + threadIdx.x;
        src = (w == 0) ? Wq : (w == 1) ? Wk : (w == 2) ? Wv : Wo;
        dst = (w == 3) ? Wob : Wqkvb + (size_t)w * 1048576;
    }
    float4 v = ((const float4*)src)[idx];
    ((uint2*)dst)[idx] = make_uint2(pack2bf(v.x, v.y), pack2bf(v.z, v.w));
}

// ---------------------------------------------------------------- fused QKV GEMM
// A: (8192,1024) bf16. Wqkv: 3 stacked (1024,1024) bf16.
// blockIdx.x: [0,8)=Q, [8,16)=K, [16,24)=V. Q scaled by QSCALE; V stored
// transposed per head: Vt[(b*1024 + n)*2048 + s]. Epilogue bounces the
// 128x128 bf16 tile through LDS (stride 136) for coalesced b128 stores.
// m97 2-barrier structure: 6 blocks/CU -> cross-block overlap hides staging.
__global__ __launch_bounds__(256) void gemm_qkv(const unsigned short* __restrict__ A,
                                                const unsigned short* __restrict__ Wqkv,
                                                const float* __restrict__ bq,
                                                const float* __restrict__ bk,
                                                const float* __restrict__ bv,
                                                unsigned short* __restrict__ Qb,
                                                unsigned short* __restrict__ Kb,
                                                unsigned short* __restrict__ Vt) {
    __shared__ alignas(16) unsigned short smem[17408];   // staging (2x8192) / out-tile (128x136)
    unsigned short* sA = smem;
    unsigned short* sB = smem + 8192;
    unsigned short* OT = smem;

    const int tid  = threadIdx.x;
    const int lane = tid & 63;
    const int wave = tid >> 6;
    const int quad = lane >> 4;
    const int l15  = lane & 15;
    const int lr   = lane >> 3;
    const int lcs  = (((lane & 7) ^ lr) << 3);
    const int nb   = blockIdx.x >> 3;              // 0=Q 1=K 2=V
    const int col0 = (blockIdx.x & 7) * 128;
    const int row0 = blockIdx.y * 128;
    const unsigned short* W = Wqkv + ((size_t)nb << 20);
    const float* bias = (nb == 0) ? bq : (nb == 1) ? bk : bv;
    const int wm = wave >> 1, wn = wave & 1;

    f32x4 acc[4][4];
#pragma unroll
    for (int i = 0; i < 4; i++)
#pragma unroll
        for (int j = 0; j < 4; j++) acc[i][j] = f32x4{0.f, 0.f, 0.f, 0.f};

    for (int kt = 0; kt < 16; ++kt) {
        const int k0 = kt * 64;
#pragma unroll
        for (int i = 0; i < 4; i++) {
            const int c = wave * 4 + i;
            const int r = c * 8 + lr;
            gld16(A + (size_t)(row0 + r) * 1024 + k0 + lcs, &sA[c * 512]);
            gld16(W + (size_t)(col0 + r) * 1024 + k0 + lcs, &sB[c * 512]);
        }
        __syncthreads();
#pragma unroll
        for (int kx = 0; kx < 2; ++kx) {
            bf16x8 a[4], b[4];
#pragma unroll
            for (int i = 0; i < 4; i++) {
                a[i] = *(const bf16x8*)&sA[swz(wm * 64 + i * 16 + l15, kx * 4 + quad)];
                b[i] = *(const bf16x8*)&sB[swz(wn * 64 + i * 16 + l15, kx * 4 + quad)];
            }
#pragma unroll
            for (int i = 0; i < 4; i++)
#pragma unroll
                for (int j = 0; j < 4; j++)
                    acc[i][j] = __builtin_amdgcn_mfma_f32_16x16x32_bf16(a[i], b[j], acc[i][j], 0, 0, 0);
        }
        __syncthreads();
    }

    // ---- epilogue phase 1: acc -> LDS out-tile (stride 136 shorts)
    if (nb != 2) {
        const float sc = (nb == 0) ? QSCALE : 1.0f;
#pragma unroll
        for (int i = 0; i < 4; i++) {
#pragma unroll
            for (int j = 0; j < 4; j++) {
                const int ct  = wn * 64 + j * 16 + l15;
                const float bvv = bias[col0 + ct];
                const int rt  = wm * 64 + i * 16 + quad * 4;
#pragma unroll
                for (int r = 0; r < 4; r++)
                    OT[(rt + r) * 136 + ct] = f2bf((acc[i][j][r] + bvv) * sc);
            }
        }
    } else {
#pragma unroll
        for (int i = 0; i < 4; i++) {
#pragma unroll
            for (int j = 0; j < 4; j++) {
                const int ct  = wn * 64 + j * 16 + l15;          // d within tile
                const float bvv = bias[col0 + ct];
                const int rt  = wm * 64 + i * 16 + quad * 4;     // s within tile
                *(uint2*)&OT[ct * 136 + rt] =
                    make_uint2(pack2bf(acc[i][j][0] + bvv, acc[i][j][1] + bvv),
                               pack2bf(acc[i][j][2] + bvv, acc[i][j][3] + bvv));
            }
        }
    }
    __syncthreads();

    // ---- epilogue phase 2: coalesced b128 stores
    const int rr   = wave * 32 + (lane >> 1);
    const int half = lane & 1;
    if (nb != 2) {
        unsigned short* C = (nb == 0) ? Qb : Kb;
        unsigned short* gdst = C + (size_t)(row0 + rr) * 1024 + col0 + half * 64;
#pragma unroll
        for (int k = 0; k < 8; k++)
            *(bf16x8*)(gdst + k * 8) = *(const bf16x8*)&OT[rr * 136 + half * 64 + k * 8];
    } else {
        const int bb = row0 >> 11, s0l = row0 & 2047;
        unsigned short* gdst = Vt + ((size_t)(bb * 1024 + col0 + rr)) * 2048 + s0l + half * 64;
#pragma unroll
        for (int k = 0; k < 8; k++)
            *(bf16x8*)(gdst + k * 8) = *(const bf16x8*)&OT[rr * 136 + half * 64 + k * 8];
    }
}

// ---------------------------------------------------------------- out GEMM (f32 out)
// R4 form (2-barrier m97): R5's dbuf variant regressed ~14us.
__global__ __launch_bounds__(256) void gemm_out(const unsigned short* __restrict__ A,
                                                const unsigned short* __restrict__ W,
                                                const float* __restrict__ bias,
                                                float* __restrict__ C) {
    __shared__ alignas(16) unsigned short sA[128 * 64];
    __shared__ alignas(16) unsigned short sB[128 * 64];
    const int tid  = threadIdx.x;
    const int lane = tid & 63;
    const int wave = tid >> 6;
    const int quad = lane >> 4;
    const int l15  = lane & 15;
    const int lr   = lane >> 3;
    const int lcs  = (((lane & 7) ^ lr) << 3);
    const int row0 = blockIdx.y * 128;
    const int col0 = blockIdx.x * 128;
    const int wm = wave >> 1, wn = wave & 1;

    f32x4 acc[4][4];
#pragma unroll
    for (int i = 0; i < 4; i++)
#pragma unroll
        for (int j = 0; j < 4; j++) acc[i][j] = f32x4{0.f, 0.f, 0.f, 0.f};

    for (int kt = 0; kt < 16; ++kt) {
        const int k0 = kt * 64;
#pragma unroll
        for (int i = 0; i < 4; i++) {
            const int c = wave * 4 + i;
            const int r = c * 8 + lr;
            gld16(A + (size_t)(row0 + r) * 1024 + k0 + lcs, &sA[c * 512]);
            gld16(W + (size_t)(col0 + r) * 1024 + k0 + lcs, &sB[c * 512]);
        }
        __syncthreads();
#pragma unroll
        for (int kx = 0; kx < 2; ++kx) {
            bf16x8 a[4], b[4];
#pragma unroll
            for (int i = 0; i < 4; i++) {
                a[i] = *(const bf16x8*)&sA[swz(wm * 64 + i * 16 + l15, kx * 4 + quad)];
                b[i] = *(const bf16x8*)&sB[swz(wn * 64 + i * 16 + l15, kx * 4 + quad)];
            }
#pragma unroll
            for (int i = 0; i < 4; i++)
#pragma unroll
                for (int j = 0; j < 4; j++)
                    acc[i][j] = __builtin_amdgcn_mfma_f32_16x16x32_bf16(a[i], b[j], acc[i][j], 0, 0, 0);
        }
        __syncthreads();
    }

#pragma unroll
    for (int i = 0; i < 4; i++) {
#pragma unroll
        for (int j = 0; j < 4; j++) {
            const int col   = col0 + wn * 64 + j * 16 + l15;
            const float bvv = bias[col];
            const int rbase = row0 + wm * 64 + i * 16 + quad * 4;
#pragma unroll
            for (int r = 0; r < 4; r++)
                C[(size_t)(rbase + r) * 1024 + col] = acc[i][j][r] + bvv;
        }
    }
}

// ---------------------------------------------------------------- flash attention
// Q, K: (B*S, 1024) bf16; Q pre-scaled by QSCALE (fold softmax scale + log2e).
// Vt: (B*1024, 2048) bf16. Ctx out: (B*S, 1024) bf16.
// Block: 256 q-rows of one (b,h), 8 waves (512 thr); wave owns 32 q-rows.
// 32 k-tiles of 64. Single-barrier dbuf prefetch. Row-sums via MFMA
// (Osum += P @ ones) -> no scalar adds, no epilogue shuffle reduction.
__global__ __launch_bounds__(512) void attn(const unsigned short* __restrict__ Q,
                                            const unsigned short* __restrict__ K,
                                            const unsigned short* __restrict__ Vt,
                                            unsigned short* __restrict__ Ctx) {
    __shared__ alignas(16) unsigned short Kl[2][4096];     // [buf][krow][d], swizzled (8KB ea)
    __shared__ alignas(16) unsigned short Vl[2][4096];     // [buf][d][krow], swizzled
    __shared__ alignas(16) unsigned short Pl[8][32][72];   // per-wave P (36KB)

    const int tid  = threadIdx.x;
    const int lane = tid & 63;
    const int wave = tid >> 6;        // 0..7
    const int quad = lane >> 4;
    const int l15  = lane & 15;
    const int lr   = lane >> 3;
    const int lcs  = (((lane & 7) ^ lr) << 3);

    const int qt = blockIdx.x, h = blockIdx.y, b = blockIdx.z;
    const int q0 = qt * 256;
    const size_t tokbase = (size_t)b * 2048;

    bf16x8 qa[2][2];
#pragma unroll
    for (int mt = 0; mt < 2; ++mt)
#pragma unroll
        for (int kx = 0; kx < 2; ++kx)
            qa[mt][kx] = *(const bf16x8*)(Q + (tokbase + q0 + wave * 32 + mt * 16 + l15) * 1024 +
                                          h * 64 + kx * 32 + quad * 8);

    f32x4 O[2][4], Osum[2];
#pragma unroll
    for (int mt = 0; mt < 2; ++mt) {
#pragma unroll
        for (int nt = 0; nt < 4; ++nt) O[mt][nt] = f32x4{0.f, 0.f, 0.f, 0.f};
        Osum[mt] = f32x4{0.f, 0.f, 0.f, 0.f};
    }
    const bf16x8 vones = {16256, 16256, 16256, 16256, 16256, 16256, 16256, 16256};  // bf16 1.0

#define AT_STAGE(kt_, buf_)                                                                     \
    {                                                                                           \
        const int rr = wave * 8 + lr;                                                           \
        gld16(K + (tokbase + (kt_) * 64 + rr) * 1024 + h * 64 + lcs, &Kl[buf_][wave * 512]);    \
        gld16(Vt + ((size_t)(b * 1024 + h * 64 + rr)) * 2048 + (kt_) * 64 + lcs,                \
              &Vl[buf_][wave * 512]);                                                           \
    }

    AT_STAGE(0, 0)
    for (int kt = 0; kt < 32; ++kt) {
        const int buf = kt & 1;
        __syncthreads();                     // publishes buf (drains prefetch vmcnt)
        if (kt < 31) AT_STAGE(kt + 1, buf ^ 1)

        // S^T = K @ Q^T  (C layout: row=quad*4+r is K-COL, col=lane&15 is Q-ROW)
        f32x4 St[4][2];
#pragma unroll
        for (int nt = 0; nt < 4; ++nt)
#pragma unroll
            for (int mt = 0; mt < 2; ++mt) St[nt][mt] = f32x4{0.f, 0.f, 0.f, 0.f};
#pragma unroll
        for (int kx = 0; kx < 2; ++kx) {
            bf16x8 kb[4];
#pragma unroll
            for (int nt = 0; nt < 4; ++nt)
                kb[nt] = *(const bf16x8*)&Kl[buf][swz(nt * 16 + l15, kx * 4 + quad)];
#pragma unroll
            for (int nt = 0; nt < 4; ++nt)
#pragma unroll
                for (int mt = 0; mt < 2; ++mt)
                    St[nt][mt] = __builtin_amdgcn_mfma_f32_16x16x32_bf16(kb[nt], qa[mt][kx], St[nt][mt], 0, 0, 0);
        }

        // raw v_exp_f32 (scores pre-scaled by log2e) + perm-pack -> b64 write
#pragma unroll
        for (int mt = 0; mt < 2; ++mt) {
#pragma unroll
            for (int nt = 0; nt < 4; ++nt) {
                float p0 = __builtin_amdgcn_exp2f(St[nt][mt][0]);
                float p1 = __builtin_amdgcn_exp2f(St[nt][mt][1]);
                float p2 = __builtin_amdgcn_exp2f(St[nt][mt][2]);
                float p3 = __builtin_amdgcn_exp2f(St[nt][mt][3]);
                *(uint2*)&Pl[wave][mt * 16 + l15][nt * 16 + quad * 4] =
                    make_uint2(pack2bf(p0, p1), pack2bf(p2, p3));
            }
        }

        // O += P @ V ; Osum += P @ ones  (row-sums on the MFMA pipe)
#pragma unroll
        for (int kx = 0; kx < 2; ++kx) {
            bf16x8 pa[2], vb[4];
#pragma unroll
            for (int mt = 0; mt < 2; ++mt)
                pa[mt] = *(const bf16x8*)&Pl[wave][mt * 16 + l15][kx * 32 + quad * 8];
#pragma unroll
            for (int nt = 0; nt < 4; ++nt)
                vb[nt] = *(const bf16x8*)&Vl[buf][swz(nt * 16 + l15, kx * 4 + quad)];
#pragma unroll
            for (int mt = 0; mt < 2; ++mt) {
#pragma unroll
                for (int nt = 0; nt < 4; ++nt)
                    O[mt][nt] = __builtin_amdgcn_mfma_f32_16x16x32_bf16(pa[mt], vb[nt], O[mt][nt], 0, 0, 0);
                Osum[mt] = __builtin_amdgcn_mfma_f32_16x16x32_bf16(pa[mt], vones, Osum[mt], 0, 0, 0);
            }
        }
    }
#undef AT_STAGE

    // normalize + store ctx; O C-layout rows = quad*4+r match Osum rows exactly
#pragma unroll
    for (int mt = 0; mt < 2; ++mt) {
#pragma unroll
        for (int r = 0; r < 4; ++r) {
            const float inv = 1.0f / Osum[mt][r];
            const int row   = q0 + wave * 32 + mt * 16 + quad * 4 + r;
            const size_t base = (tokbase + row) * 1024 + h * 64;
#pragma unroll
            for (int nt = 0; nt < 4; ++nt)
                Ctx[base + nt * 16 + l15] = f2bf(O[mt][nt][r] * inv);
        }
    }
}

// ---------------------------------------------------------------- launch
extern "C" void kernel_launch(void* const* d_in, const int* in_sizes, int n_in,
                              void* d_out, int out_size, void* d_ws, size_t ws_size,
                              hipStream_t stream) {
    (void)in_sizes; (void)n_in; (void)out_size; (void)ws_size;
    const float* X  = (const float*)d_in[0];
    const float* Wq = (const float*)d_in[1];
    const float* bq = (const float*)d_in[2];
    const float* Wk = (const float*)d_in[3];
    const float* bk = (const float*)d_in[4];
    const float* Wv = (const float*)d_in[5];
    const float* bv = (const float*)d_in[6];
    const float* Wo = (const float*)d_in[7];
    const float* bo = (const float*)d_in[8];

    char* ws = (char*)d_ws;
    unsigned short* Xb    = (unsigned short*)(ws);                        // 16 MB (aliased as Ctx)
    unsigned short* Qb    = (unsigned short*)(ws + (size_t)16 * 1048576); // 16 MB
    unsigned short* Kb    = (unsigned short*)(ws + (size_t)32 * 1048576); // 16 MB
    unsigned short* Vt    = (unsigned short*)(ws + (size_t)48 * 1048576); // 16 MB
    unsigned short* Wqkvb = (unsigned short*)(ws + (size_t)64 * 1048576); // 6 MB
    unsigned short* Wob   = (unsigned short*)(ws + (size_t)70 * 1048576); // 2 MB
    unsigned short* Ctx   = Xb;  // X dead after QKV GEMM (stream-ordered)

    castall<<<dim3(12288), 256, 0, stream>>>(X, Wq, Wk, Wv, Wo, Xb, Wqkvb, Wob);
    gemm_qkv<<<dim3(24, 64), 256, 0, stream>>>(Xb, Wqkvb, bq, bk, bv, Qb, Kb, Vt);
    attn<<<dim3(8, 16, 4), 512, 0, stream>>>(Qb, Kb, Vt, Ctx);
    gemm_out<<<dim3(8, 64), 256, 0, stream>>>(Ctx, Wob, bo, (float*)d_out);
}